// Round 5
// baseline (214.801 us; speedup 1.0000x reference)
//
#include <hip/hip_runtime.h>
#include <math.h>

#define AN 4096
#define CN 8
#define FN 64
#define ACN (AN*CN)   // 32768

typedef __attribute__((ext_vector_type(8))) short bf16x8;
typedef __attribute__((ext_vector_type(4))) float f32x4;

__device__ inline unsigned short f2bf(float f) {
    unsigned u = __float_as_uint(f);
    unsigned r = ((u >> 16) & 1) + 0x7FFFu;   // round-to-nearest-even
    return (unsigned short)((u + r) >> 16);
}

// ===========================================================================
// DIAGNOSTIC ROUND: bodies are the round-2 (91.9 us) versions, but k1/k2/k3
// grids are replicated x16/x6/x16 so each dispatch exceeds the ~43 us
// workspace-fill rows and becomes visible in rocprof top-5 WITH counters.
// Replicas write identical values to identical addresses (aligned 32-bit
// stores) -> result bit-exact. dur_us is intentionally inflated this round.
// ===========================================================================

// ---------------------------------------------------------------------------
// K1: normalize -> xnb bf16 [c][a][f] + inv[a*8+c]. Replicated x16.
// ---------------------------------------------------------------------------
__global__ __launch_bounds__(256) void k1_normalize(const float* __restrict__ x,
                                                    unsigned short* __restrict__ xnb,
                                                    float* __restrict__ inv)
{
    int blk  = blockIdx.x & 511;            // 16 replicas
    int tid  = threadIdx.x;
    int grp  = tid >> 4;
    int slot = tid & 15;
    #pragma unroll
    for (int s = 0; s < 4; ++s) {
        int V = blk * 64 + s * 16 + grp;    // 0..32767 = a*8+c
        const float4 v = *(const float4*)(x + (size_t)V * FN + slot * 4);
        float ss = v.x*v.x + v.y*v.y + v.z*v.z + v.w*v.w;
        ss += __shfl_xor(ss, 1);
        ss += __shfl_xor(ss, 2);
        ss += __shfl_xor(ss, 4);
        ss += __shfl_xor(ss, 8);
        float sc = 1.0f / fmaxf(sqrtf(ss), 1e-6f);
        int a = V >> 3, c = V & 7;
        ushort4 ob;
        ob.x = f2bf(v.x * sc); ob.y = f2bf(v.y * sc);
        ob.z = f2bf(v.z * sc); ob.w = f2bf(v.w * sc);
        *(ushort4*)(xnb + ((size_t)c * AN + a) * FN + slot * 4) = ob;
        if (slot == 0) inv[V] = sc;
    }
}

// ---------------------------------------------------------------------------
// K2: round-2 body (2x2 quadrants, reg-staged prefetch + ds_write, per-iter
// barrier). Replicated x6.
// ---------------------------------------------------------------------------
__global__ __launch_bounds__(256, 2) void k2_argmax(const unsigned short* __restrict__ xnb,
                                                    unsigned int* __restrict__ pP)
{
    __shared__ uint4 lds4[3 * 1024];   // At [0,1024) | Bt0 [1024,2048) | Bt1 [2048,3072)

    int blk  = blockIdx.x & 511;       // 6 replicas
    int half = blk & 1;
    int rt   = (blk >> 1) & 31;
    int c    = blk >> 6;
    int a0   = rt * 128;
    int b0base = half * 2048;

    const uint4* __restrict__ Xc4 = (const uint4*)(xnb + (size_t)c * AN * FN);

    int tid  = threadIdx.x;
    int lane = tid & 63;
    int w    = tid >> 6;
    int wr   = w >> 1;        // row quadrant 0..1
    int wc   = w & 1;         // col quadrant 0..1
    int l15  = lane & 15;
    int quad = lane >> 4;

    int srow   = tid >> 3;    // staging row base 0..31
    int schunk = tid & 7;     // staging 16B chunk 0..7

    // ---- stage A tile ----
    #pragma unroll
    for (int s = 0; s < 4; ++s) {
        int r = srow + 32 * s;
        lds4[r * 8 + (schunk ^ (r & 7))] = Xc4[(size_t)(a0 + r) * 8 + schunk];
    }
    // ---- stage B tile 0 ----
    #pragma unroll
    for (int s = 0; s < 4; ++s) {
        int r = srow + 32 * s;
        lds4[1024 + r * 8 + (schunk ^ (r & 7))] = Xc4[(size_t)(b0base + r) * 8 + schunk];
    }
    __syncthreads();

    // ---- A fragments into registers (loop-invariant) ----
    bf16x8 afr[4][2];
    #pragma unroll
    for (int mi = 0; mi < 4; ++mi)
        #pragma unroll
        for (int ks = 0; ks < 2; ++ks) {
            int r  = wr * 64 + mi * 16 + l15;
            int ch = (ks * 4 + quad) ^ (r & 7);
            afr[mi][ks] = ((const bf16x8*)lds4)[r * 8 + ch];
        }

    float bestp[16];
    #pragma unroll
    for (int i = 0; i < 16; ++i) bestp[i] = 0.0f;

    const f32x4 two = {2.0f, 2.0f, 2.0f, 2.0f};

    for (int it = 0; it < 16; ++it) {
        int cur = it & 1;
        // prefetch next B tile into registers
        uint4 gv[4];
        if (it < 15) {
            int g0 = b0base + (it + 1) * 128;
            #pragma unroll
            for (int s = 0; s < 4; ++s)
                gv[s] = Xc4[(size_t)(g0 + srow + 32 * s) * 8 + schunk];
        }

        // ---- MFMA on buffer cur ----
        f32x4 acc[4][4];
        const bf16x8* bt = (const bf16x8*)(lds4 + 1024 + cur * 1024);
        #pragma unroll
        for (int ks = 0; ks < 2; ++ks) {
            #pragma unroll
            for (int ni = 0; ni < 4; ++ni) {
                int r  = wc * 64 + ni * 16 + l15;
                int ch = (ks * 4 + quad) ^ (r & 7);
                bf16x8 bfr = bt[r * 8 + ch];
                #pragma unroll
                for (int mi = 0; mi < 4; ++mi)
                    acc[mi][ni] = __builtin_amdgcn_mfma_f32_16x16x32_bf16(
                        afr[mi][ks], bfr, (ks == 0) ? two : acc[mi][ni], 0, 0, 0);
            }
        }

        // ---- packed argmax update (gather-4 then max3-reduce) ----
        int colblk = b0base + it * 128 + wc * 64;
        int codebase = colblk + l15;
        #pragma unroll
        for (int mi = 0; mi < 4; ++mi) {
            int rfrag = a0 + wr * 64 + mi * 16;
            #pragma unroll
            for (int r = 0; r < 4; ++r) {
                float cand[4];
                #pragma unroll
                for (int ni = 0; ni < 4; ++ni) {
                    unsigned pb = (__float_as_uint(acc[mi][ni][r]) & 0xFFFFF000u)
                                | (unsigned)(codebase + ni * 16);
                    cand[ni] = __uint_as_float(pb);
                }
                #pragma unroll
                for (int ni = 0; ni < 4; ++ni) {
                    if (rfrag == colblk + ni * 16) {         // wave-uniform
                        if (l15 == quad * 4 + r) cand[ni] = 0.0f;
                    }
                }
                int bi = mi * 4 + r;
                bestp[bi] = fmaxf(fmaxf(fmaxf(fmaxf(cand[0], cand[1]), cand[2]),
                                        cand[3]), bestp[bi]);
            }
        }

        // ---- write prefetched tile into other buffer ----
        if (it < 15) {
            #pragma unroll
            for (int s = 0; s < 4; ++s) {
                int r = srow + 32 * s;
                lds4[1024 + (cur ^ 1) * 1024 + r * 8 + (schunk ^ (r & 7))] = gv[s];
            }
        }
        __syncthreads();
    }

    // ---- reduce across the 16 column-lanes ----
    #pragma unroll
    for (int i = 0; i < 16; ++i) {
        float v = bestp[i];
        v = fmaxf(v, __shfl_xor(v, 1));
        v = fmaxf(v, __shfl_xor(v, 2));
        v = fmaxf(v, __shfl_xor(v, 4));
        v = fmaxf(v, __shfl_xor(v, 8));
        bestp[i] = v;
    }
    __syncthreads();                    // At region now reusable
    float* red = (float*)lds4;          // red[w][64]
    if (l15 == 0) {
        #pragma unroll
        for (int mi = 0; mi < 4; ++mi)
            #pragma unroll
            for (int r = 0; r < 4; ++r)
                red[w * 64 + mi * 16 + quad * 4 + r] = bestp[mi * 4 + r];
    }
    __syncthreads();
    if (tid < 128) {
        int wr2 = tid >> 6, r64 = tid & 63;
        float p = fmaxf(red[(2 * wr2) * 64 + r64], red[(2 * wr2 + 1) * 64 + r64]);
        int a = a0 + tid;
        pP[(size_t)half * ACN + (size_t)a * CN + c] = __float_as_uint(p);
    }
}

// ---------------------------------------------------------------------------
// K3: merge halves, unpack index, exact fp32 distance + log. Replicated x16.
// ---------------------------------------------------------------------------
__global__ __launch_bounds__(256) void k3_dist(const float* __restrict__ x,
                                               const float* __restrict__ inv,
                                               const unsigned int* __restrict__ pP,
                                               float* __restrict__ partials)
{
    int blk = blockIdx.x & 127;        // 16 replicas
    int tid = threadIdx.x;
    int id = blk * 256 + tid;          // a*8 + c
    float p0 = __uint_as_float(pP[id]);
    float p1 = __uint_as_float(pP[ACN + id]);
    unsigned pm = __float_as_uint(fmaxf(p0, p1));
    int m = (int)(pm & 0xFFFu);
    int c = id & 7;
    int idb = m * CN + c;
    float sa = inv[id];
    float sb = inv[idb];
    const float* xa = x + (size_t)id  * FN;
    const float* xb = x + (size_t)idb * FN;
    float ss = 0.0f;
    #pragma unroll
    for (int q = 0; q < 16; ++q) {
        float4 va = *(const float4*)(xa + 4 * q);
        float4 vb = *(const float4*)(xb + 4 * q);
        float d0 = va.x * sa - vb.x * sb + 1e-6f;
        float d1 = va.y * sa - vb.y * sb + 1e-6f;
        float d2 = va.z * sa - vb.z * sb + 1e-6f;
        float d3 = va.w * sa - vb.w * sb + 1e-6f;
        ss += d0*d0 + d1*d1 + d2*d2 + d3*d3;
    }
    float val = logf(sqrtf(ss) + 1e-6f);

    float t = val;
    #pragma unroll
    for (int off = 32; off > 0; off >>= 1) t += __shfl_down(t, off);
    __shared__ float ws4[4];
    if ((tid & 63) == 0) ws4[tid >> 6] = t;
    __syncthreads();
    if (tid == 0)
        partials[blk] = ws4[0] + ws4[1] + ws4[2] + ws4[3];
}

// ---------------------------------------------------------------------------
// K4: out = -sum(partials)/32768
// ---------------------------------------------------------------------------
__global__ __launch_bounds__(64) void k4_final(const float* __restrict__ partials,
                                               float* __restrict__ out)
{
    int t = threadIdx.x;
    float v = partials[t] + partials[t + 64];
    #pragma unroll
    for (int off = 32; off > 0; off >>= 1) v += __shfl_down(v, off);
    if (t == 0) out[0] = -v / (float)ACN;
}

extern "C" void kernel_launch(void* const* d_in, const int* in_sizes, int n_in,
                              void* d_out, int out_size, void* d_ws, size_t ws_size,
                              hipStream_t stream)
{
    const float* x = (const float*)d_in[0];
    unsigned short* xnb = (unsigned short*)d_ws;               // 4 MB bf16 [c][a][f]
    float* inv = (float*)(xnb + (size_t)AN * CN * FN);         // 128 KB inverse norms
    unsigned int* pP = (unsigned int*)(inv + ACN);             // 256 KB packed argmax
    float* partials = (float*)(pP + 2 * ACN);                  // 512 B

    // Diagnostic replication: x16 / x6 / x16 (bit-exact; see header comment).
    k1_normalize<<<512 * 16, 256, 0, stream>>>(x, xnb, inv);
    k2_argmax  <<<512 * 6,  256, 0, stream>>>(xnb, pP);
    k3_dist    <<<128 * 16, 256, 0, stream>>>(x, inv, pP, partials);
    k4_final   <<<1, 64, 0, stream>>>(partials, (float*)d_out);
}

// Round 6
// 93.285 us; speedup vs baseline: 2.3026x; 2.3026x over previous
//
#include <hip/hip_runtime.h>
#include <math.h>

#define AN 4096
#define CN 8
#define FN 64
#define ACN (AN*CN)   // 32768

typedef __attribute__((ext_vector_type(8))) short bf16x8;
typedef __attribute__((ext_vector_type(4))) float f32x4;

// Direct global->LDS DMA, 16B per lane: lane l writes lds_dest + l*16.
// LDS dest must be wave-uniform; global src per-lane (m104/m173).
#define GLL16(gsrc, ldst) \
    __builtin_amdgcn_global_load_lds( \
        (const __attribute__((address_space(1))) void*)(gsrc), \
        (__attribute__((address_space(3))) void*)(ldst), 16, 0, 0)

__device__ inline unsigned short f2bf(float f) {
    unsigned u = __float_as_uint(f);
    unsigned r = ((u >> 16) & 1) + 0x7FFFu;   // round-to-nearest-even
    return (unsigned short)((u + r) >> 16);
}

// ---------------------------------------------------------------------------
// K1: normalize -> xnb bf16 [c][a][f] (MFMA operand) + inv[a*8+c] fp32
// inverse norms. k3 recomputes x*inv (identical multiply, bit-exact).
// ---------------------------------------------------------------------------
__global__ __launch_bounds__(256) void k1_normalize(const float* __restrict__ x,
                                                    unsigned short* __restrict__ xnb,
                                                    float* __restrict__ inv)
{
    int tid  = threadIdx.x;
    int grp  = tid >> 4;
    int slot = tid & 15;
    #pragma unroll
    for (int s = 0; s < 4; ++s) {
        int V = blockIdx.x * 64 + s * 16 + grp;      // 0..32767 = a*8+c
        const float4 v = *(const float4*)(x + (size_t)V * FN + slot * 4);
        float ss = v.x*v.x + v.y*v.y + v.z*v.z + v.w*v.w;
        ss += __shfl_xor(ss, 1);
        ss += __shfl_xor(ss, 2);
        ss += __shfl_xor(ss, 4);
        ss += __shfl_xor(ss, 8);
        float sc = 1.0f / fmaxf(sqrtf(ss), 1e-6f);
        int a = V >> 3, c = V & 7;
        ushort4 ob;
        ob.x = f2bf(v.x * sc); ob.y = f2bf(v.y * sc);
        ob.z = f2bf(v.z * sc); ob.w = f2bf(v.w * sc);
        *(ushort4*)(xnb + ((size_t)c * AN + a) * FN + slot * 4) = ob;
        if (slot == 0) inv[V] = sc;
    }
}

// ---------------------------------------------------------------------------
// K2: MFMA sim + packed argmax. VALU-minimized steady state (r5 diagnosis:
// VALUBusy 66% >> MfmaUtil 36%; the excess was per-iter address VALU).
//  - full 16x unroll, 4 B-buffers: LDS byte offsets all compile-time
//    immediates on 2 per-lane base regs (r&7==l15&7 -> swizzle chunk is
//    lane-constant; ks toggles addr^64)
//  - global_load_lds staging (no ds_write, no staging regs); per-tile just a
//    pointer bump; sub-loads fold into the 13-bit global offset imm
//  - barrier-free K-loop (B slabs wave-private: wave w stages AND reads bytes
//    [w*4096,(w+1)*4096) of each buffer), counted vmcnt(12): 3 tiles in flight
//  - argmax gather-2 + max3; fmax exact+associative -> pP bit-identical
// LDS 80KB: A[0,16K) | B0..B3. 2 blocks/CU = 160KB (full LDS).
// ---------------------------------------------------------------------------
__global__ __launch_bounds__(256, 2) void k2_argmax(const unsigned short* __restrict__ xnb,
                                                    unsigned int* __restrict__ pP)
{
    __shared__ char ldsc[5 * 16384];   // A | B0 | B1 | B2 | B3

    int blk  = blockIdx.x;
    int half = blk & 1;
    int rt   = (blk >> 1) & 31;
    int c    = blk >> 6;
    int a0   = rt * 128;
    int b0base = half * 2048;

    const char* __restrict__ Xc = (const char*)(xnb + (size_t)c * AN * FN); // row r at byte r*128

    int tid  = threadIdx.x;
    int lane = tid & 63;
    int w    = tid >> 6;      // wave 0..3 -> col group w*32, staging slab w*32 rows
    int l15  = lane & 15;
    int quad = lane >> 4;
    int srow = lane >> 3;     // 0..7
    int sslot = lane & 7;

    // per-lane global staging offset within a 32-row slab (s adds 1024 via imm):
    // row_local = s*8+srow, chunk = sslot^srow  (row&7 == srow)
    int gl_lane = srow * 128 + ((sslot ^ srow) << 4);
    const char* gA = Xc + (size_t)(a0 + w * 32) * 128 + gl_lane;
    const char* gB = Xc + (size_t)(b0base + w * 32) * 128 + gl_lane;
    char* ldsA = ldsc + w * 4096;             // wave slab in A region
    char* ldsB = ldsc + 16384 + w * 4096;     // wave slab in B0; +((it&3)*16384)

    // ---- stage A tile (4 DMA / wave) ----
    GLL16(gA,        ldsA);
    GLL16(gA + 1024, ldsA + 1024);
    GLL16(gA + 2048, ldsA + 2048);
    GLL16(gA + 3072, ldsA + 3072);
    __syncthreads();          // compiler drains vmcnt before s_barrier: A visible

    // ---- A fragments: 2 base addrs + immediates ----
    // byte(mi,ks) = mi*2048 + l15*128 + ((ks*4+quad)^(l15&7))*16 ; ks flips ^64
    int ab0 = l15 * 128 + ((quad ^ (l15 & 7)) << 4);
    int ab1 = ab0 ^ 64;
    bf16x8 afr[8][2];
    #pragma unroll
    for (int mi = 0; mi < 8; ++mi) {
        afr[mi][0] = *(const bf16x8*)(ldsc + ab0 + mi * 2048);
        afr[mi][1] = *(const bf16x8*)(ldsc + ab1 + mi * 2048);
    }

    // ---- B frag base addrs (r = w*32 + ni*16 + l15; ni adds 2048 via imm) ----
    int rb0 = 16384 + (w * 32 + l15) * 128 + ((quad ^ (l15 & 7)) << 4);
    int rb1 = rb0 ^ 64;

    float bestp[32];
    #pragma unroll
    for (int i = 0; i < 32; ++i) bestp[i] = 0.0f;

    const f32x4 two = {2.0f, 2.0f, 2.0f, 2.0f};

    // ---- B staging macro: one pointer bump per tile, rest immediates ----
#define STAGE_B(IT) do { \
        const char* _g = gB + (size_t)(IT) * 16384; \
        char* _l = ldsB + ((IT) & 3) * 16384; \
        GLL16(_g,        _l); \
        GLL16(_g + 1024, _l + 1024); \
        GLL16(_g + 2048, _l + 2048); \
        GLL16(_g + 3072, _l + 3072); \
    } while (0)

    // prefetch tiles 0..2 (12 outstanding DMAs on this wave)
    STAGE_B(0);
    STAGE_B(1);
    STAGE_B(2);

    #pragma unroll
    for (int it = 0; it < 16; ++it) {
        if (it <= 12) STAGE_B(it + 3);          // 16 outstanding after issue

        // tile 'it' landed when <=12 (=3 tiles) remain in flight
        if (it <= 12)      { asm volatile("s_waitcnt vmcnt(12)" ::: "memory"); }
        else if (it == 13) { asm volatile("s_waitcnt vmcnt(8)"  ::: "memory"); }
        else if (it == 14) { asm volatile("s_waitcnt vmcnt(4)"  ::: "memory"); }
        else               { asm volatile("s_waitcnt vmcnt(0)"  ::: "memory"); }

        const int bo = (it & 3) * 16384;        // compile-time (full unroll)

        f32x4 acc[8][2];
        #pragma unroll
        for (int ks = 0; ks < 2; ++ks) {
            #pragma unroll
            for (int ni = 0; ni < 2; ++ni) {
                bf16x8 bfr = *(const bf16x8*)(ldsc + (ks ? rb1 : rb0) + bo + ni * 2048);
                #pragma unroll
                for (int mi = 0; mi < 8; ++mi)
                    acc[mi][ni] = __builtin_amdgcn_mfma_f32_16x16x32_bf16(
                        afr[mi][ks], bfr, (ks == 0) ? two : acc[mi][ni], 0, 0, 0);
            }
        }

        // ---- packed argmax update ----
        int colblk = b0base + it * 128 + w * 32;
        #pragma unroll
        for (int mi = 0; mi < 8; ++mi) {
            int rfrag = a0 + mi * 16;
            #pragma unroll
            for (int r = 0; r < 4; ++r) {
                unsigned p0 = (__float_as_uint(acc[mi][0][r]) & 0xFFFFF000u)
                            | (unsigned)(colblk + l15);
                unsigned p1 = (__float_as_uint(acc[mi][1][r]) & 0xFFFFF000u)
                            | (unsigned)(colblk + 16 + l15);
                float c0 = __uint_as_float(p0);
                float c1 = __uint_as_float(p1);
                if (rfrag == colblk) {                    // wave-uniform
                    if (l15 == quad * 4 + r) c0 = 0.0f;
                }
                if (rfrag == colblk + 16) {               // wave-uniform
                    if (l15 == quad * 4 + r) c1 = 0.0f;
                }
                int bi = mi * 4 + r;
                bestp[bi] = fmaxf(fmaxf(c0, c1), bestp[bi]);
            }
        }
    }
#undef STAGE_B

    // ---- reduce across the 16 column-lanes ----
    #pragma unroll
    for (int i = 0; i < 32; ++i) {
        float v = bestp[i];
        v = fmaxf(v, __shfl_xor(v, 1));
        v = fmaxf(v, __shfl_xor(v, 2));
        v = fmaxf(v, __shfl_xor(v, 4));
        v = fmaxf(v, __shfl_xor(v, 8));
        bestp[i] = v;
    }
    __syncthreads();                    // all waves done; A region reusable
    float* red = (float*)ldsc;          // red[w][128]
    if (l15 == 0) {
        #pragma unroll
        for (int mi = 0; mi < 8; ++mi)
            #pragma unroll
            for (int r = 0; r < 4; ++r)
                red[w * 128 + mi * 16 + quad * 4 + r] = bestp[mi * 4 + r];
    }
    __syncthreads();
    if (tid < 128) {
        float p = fmaxf(fmaxf(red[tid], red[128 + tid]),
                        fmaxf(red[256 + tid], red[384 + tid]));
        int a = a0 + tid;
        pP[(size_t)half * ACN + (size_t)a * CN + c] = __float_as_uint(p);
    }
}

// ---------------------------------------------------------------------------
// K3: merge halves, unpack index, exact fp32 distance (x*inv recomputes the
// normalized values with identical multiplies) + log, block-reduce.
// ---------------------------------------------------------------------------
__global__ __launch_bounds__(256) void k3_dist(const float* __restrict__ x,
                                               const float* __restrict__ inv,
                                               const unsigned int* __restrict__ pP,
                                               float* __restrict__ partials)
{
    int tid = threadIdx.x;
    int id = blockIdx.x * 256 + tid;            // a*8 + c
    float p0 = __uint_as_float(pP[id]);
    float p1 = __uint_as_float(pP[ACN + id]);
    unsigned pm = __float_as_uint(fmaxf(p0, p1));
    int m = (int)(pm & 0xFFFu);
    int c = id & 7;
    int idb = m * CN + c;
    float sa = inv[id];
    float sb = inv[idb];
    const float* xa = x + (size_t)id  * FN;
    const float* xb = x + (size_t)idb * FN;
    float ss = 0.0f;
    #pragma unroll
    for (int q = 0; q < 16; ++q) {
        float4 va = *(const float4*)(xa + 4 * q);
        float4 vb = *(const float4*)(xb + 4 * q);
        float d0 = va.x * sa - vb.x * sb + 1e-6f;
        float d1 = va.y * sa - vb.y * sb + 1e-6f;
        float d2 = va.z * sa - vb.z * sb + 1e-6f;
        float d3 = va.w * sa - vb.w * sb + 1e-6f;
        ss += d0*d0 + d1*d1 + d2*d2 + d3*d3;
    }
    float val = logf(sqrtf(ss) + 1e-6f);

    float t = val;
    #pragma unroll
    for (int off = 32; off > 0; off >>= 1) t += __shfl_down(t, off);
    __shared__ float ws4[4];
    if ((tid & 63) == 0) ws4[tid >> 6] = t;
    __syncthreads();
    if (tid == 0)
        partials[blockIdx.x] = ws4[0] + ws4[1] + ws4[2] + ws4[3];
}

// ---------------------------------------------------------------------------
// K4: out = -sum(partials)/32768
// ---------------------------------------------------------------------------
__global__ __launch_bounds__(64) void k4_final(const float* __restrict__ partials,
                                               float* __restrict__ out)
{
    int t = threadIdx.x;
    float v = partials[t] + partials[t + 64];
    #pragma unroll
    for (int off = 32; off > 0; off >>= 1) v += __shfl_down(v, off);
    if (t == 0) out[0] = -v / (float)ACN;
}

extern "C" void kernel_launch(void* const* d_in, const int* in_sizes, int n_in,
                              void* d_out, int out_size, void* d_ws, size_t ws_size,
                              hipStream_t stream)
{
    const float* x = (const float*)d_in[0];
    unsigned short* xnb = (unsigned short*)d_ws;               // 4 MB bf16 [c][a][f]
    float* inv = (float*)(xnb + (size_t)AN * CN * FN);         // 128 KB inverse norms
    unsigned int* pP = (unsigned int*)(inv + ACN);             // 256 KB packed argmax
    float* partials = (float*)(pP + 2 * ACN);                  // 512 B

    k1_normalize<<<512, 256, 0, stream>>>(x, xnb, inv);
    k2_argmax  <<<512, 256, 0, stream>>>(xnb, pP);
    k3_dist    <<<128, 256, 0, stream>>>(x, inv, pP, partials);
    k4_final   <<<1, 64, 0, stream>>>(partials, (float*)d_out);
}